// Round 4
// baseline (278.077 us; speedup 1.0000x reference)
//
#include <hip/hip_runtime.h>

#define NP 8
#define TPB 256

// Fused CIoU. Intersection area via Green's theorem on clipped edges:
//   2*area(A∩B) = sum_{edges e of A} cross(P_e(t0),P_e(t1)) with [t0,t1]
//                 clipped to B's half-planes   +  symmetric for B vs A.
// Fully unrolled, register-resident, branchless. All divides are
// __fdividef (rcp+mul) — plain fp32 '/' emits the div_scale/div_fixup
// sequence and (round 3) caused catastrophic spilling.
__global__ __launch_bounds__(TPB, 4) void ciou_fused(
    const float* __restrict__ A,
    const float* __restrict__ Bq,
    float* __restrict__ out,
    double* __restrict__ acc,
    unsigned int* __restrict__ cnt,
    int nbatch, int nblocks)
{
    const int t = threadIdx.x;
    const int i = blockIdx.x * TPB + t;
    float val = 0.f;

    if (i < nbatch) {
        float ax[NP], ay[NP], bx[NP], by[NP];
        const float4* pa = (const float4*)(A + (size_t)i * (2 * NP));
        const float4* pb = (const float4*)(Bq + (size_t)i * (2 * NP));
        #pragma unroll
        for (int j = 0; j < NP / 2; ++j) {
            float4 v0 = pa[j];
            ax[2*j] = v0.x; ay[2*j] = v0.y; ax[2*j+1] = v0.z; ay[2*j+1] = v0.w;
            float4 v1 = pb[j];
            bx[2*j] = v1.x; by[2*j] = v1.y; bx[2*j+1] = v1.z; by[2*j+1] = v1.w;
        }

        // Areas (input vertex order is CCW; sort_poly is a pure rotation).
        float area_a = 0.f, area_b = 0.f;
        #pragma unroll
        for (int j = 0; j < NP; ++j) {
            int k = (j + 1) & (NP - 1);
            area_a += ax[j] * ay[k] - ay[j] * ax[k];
            area_b += bx[j] * by[k] - by[j] * bx[k];
        }
        area_a *= 0.5f; area_b *= 0.5f;

        // ---- Intersection: sum over P's edges clipped to Q's half-planes ----
        auto clip_dir = [](const float (&px)[NP], const float (&py)[NP],
                           const float (&qx)[NP], const float (&qy)[NP]) -> float {
            float s = 0.f;
            #pragma unroll
            for (int e = 0; e < NP; ++e) {
                int en = (e + 1) & (NP - 1);
                float Px = px[e], Py = py[e];
                float Dx = px[en] - Px, Dy = py[en] - Py;
                float t0 = 0.f, t1 = 1.f;
                bool empty = false;
                #pragma unroll
                for (int j = 0; j < NP; ++j) {
                    int jn = (j + 1) & (NP - 1);
                    float ex = qx[jn] - qx[j], ey = qy[jn] - qy[j];
                    // inside Q: cross(E_Q, p - V_Q) >= 0  ->  a + t*b >= 0
                    float a = ex * (Py - qy[j]) - ey * (Px - qx[j]);
                    float b = ex * Dy - ey * Dx;
                    float tc = __fdividef(-a, b);   // used only when b != 0
                    bool bp = b > 0.f, bn = b < 0.f;
                    t0 = (bp && tc > t0) ? tc : t0;
                    t1 = (bn && tc < t1) ? tc : t1;
                    empty = empty || (!bp && !bn && a < 0.f);
                }
                t0 = fminf(fmaxf(t0, 0.f), 1.f);
                t1 = fminf(fmaxf(t1, 0.f), 1.f);
                bool ok = (t1 > t0) && !empty;
                float P0x = Px + t0 * Dx, P0y = Py + t0 * Dy;
                float P1x = Px + t1 * Dx, P1y = Py + t1 * Dy;
                float c = P0x * P1y - P0y * P1x;
                s += ok ? c : 0.f;
            }
            return s;
        };
        float inter2 = clip_dir(ax, ay, bx, by) + clip_dir(bx, by, ax, ay);
        float inter = fmaxf(0.5f * inter2, 0.f);

        float uni = area_a + area_b - inter;
        float iou = inter / uni;

        // ---- Convex hull area of 16 points: register Jarvis march ----
        float stx = ax[0], sty = ay[0];
        {
            auto upd = [&](float px, float py) {
                bool b = (py < sty) || (py == sty && px < stx);
                stx = b ? px : stx; sty = b ? py : sty;
            };
            #pragma unroll
            for (int j = 1; j < NP; ++j) upd(ax[j], ay[j]);
            #pragma unroll
            for (int j = 0; j < NP; ++j) upd(bx[j], by[j]);
        }
        float cxv = stx, cyv = sty;
        float accH = 0.f;
        bool done = false;
        for (int it = 0; it < 16; ++it) {
            float nx = cxv, ny = cyv;
            float cdx = 0.f, cdy = 0.f;
            bool cv = false;
            auto scan = [&](float px, float py) {
                float vx = px - cxv, vy = py - cyv;
                bool valid = (vx * vx + vy * vy) > 1e-16f;
                float cr = cdx * vy - cdy * vx;   // p right of cur->cand?
                bool take = valid && (!cv || cr < 0.f);
                nx = take ? px : nx;  ny = take ? py : ny;
                cdx = take ? vx : cdx; cdy = take ? vy : cdy;
                cv = cv || valid;
            };
            #pragma unroll
            for (int j = 0; j < NP; ++j) scan(ax[j], ay[j]);
            #pragma unroll
            for (int j = 0; j < NP; ++j) scan(bx[j], by[j]);
            accH += done ? 0.f : (cxv * ny - cyv * nx);
            done = done || (nx == stx && ny == sty);
            cxv = nx; cyv = ny;
            if (__all(done)) break;
        }
        float ch = 0.5f * accH;

        val = iou - (ch - uni) / ch;
    }

    // ---- reduction: wave shuffle -> LDS(16B) -> global double atomic ----
    float v = val;
    #pragma unroll
    for (int off = 32; off > 0; off >>= 1) v += __shfl_down(v, off);
    __shared__ float wsum[4];
    int lane = t & 63, wid = t >> 6;
    if (lane == 0) wsum[wid] = v;
    __syncthreads();
    if (t == 0) {
        double bsum = (double)wsum[0] + (double)wsum[1]
                    + (double)wsum[2] + (double)wsum[3];
        atomicAdd(acc, bsum);
        __threadfence();
        unsigned int old = atomicAdd(cnt, 1u);
        if (old == (unsigned int)(nblocks - 1)) {
            double total = atomicAdd(acc, 0.0);   // read after all adds visible
            out[0] = (float)(total / (double)nbatch);
        }
    }
}

extern "C" void kernel_launch(void* const* d_in, const int* in_sizes, int n_in,
                              void* d_out, int out_size, void* d_ws, size_t ws_size,
                              hipStream_t stream) {
    const float* a = (const float*)d_in[0];
    const float* b = (const float*)d_in[1];
    float* out = (float*)d_out;
    int nbatch = in_sizes[0] / (2 * NP);
    int nblocks = (nbatch + TPB - 1) / TPB;
    double* acc = (double*)d_ws;                          // [0,8): double sum
    unsigned int* cnt = (unsigned int*)((char*)d_ws + 8); // [8,12): counter
    hipMemsetAsync(d_ws, 0, 16, stream);
    ciou_fused<<<nblocks, TPB, 0, stream>>>(a, b, out, acc, cnt, nbatch, nblocks);
}

// Round 5
// 129.500 us; speedup vs baseline: 2.1473x; 2.1473x over previous
//
#include <hip/hip_runtime.h>

#define TPB 256

// Fused CIoU. Intersection area via Green's theorem on clipped edges:
//   2*area(A∩B) = sum over directed edges of A of cross(P(t0),P(t1)) with
//   [t0,t1] clipped to B's half-planes, + symmetric for B vs A.
//
// ALL geometry state lives in named scalar variables; the clip and hull
// scans are macro-generated straight-line code. Rounds 3/4 showed that
// array-based versions (lambda by-ref / big forced-unroll loops) defeat
// SROA and dump the arrays into scratch (WRITE_SIZE 245-339 MB). Named
// scalars cannot be demoted to scratch short of cap-spill; cap is 170
// VGPRs via __launch_bounds__(TPB,3).
__global__ __launch_bounds__(TPB, 3) void ciou_fused(
    const float* __restrict__ A,
    const float* __restrict__ Bq,
    float* __restrict__ out,
    double* __restrict__ acc,
    unsigned int* __restrict__ cnt,
    int nbatch, int nblocks)
{
    const int t = threadIdx.x;
    const int i = blockIdx.x * TPB + t;
    float val = 0.f;

    if (i < nbatch) {
        float ax0,ax1,ax2,ax3,ax4,ax5,ax6,ax7;
        float ay0,ay1,ay2,ay3,ay4,ay5,ay6,ay7;
        float bx0,bx1,bx2,bx3,bx4,bx5,bx6,bx7;
        float by0,by1,by2,by3,by4,by5,by6,by7;
        {
            const float4* pa = (const float4*)(A + (size_t)i * 16);
            const float4* pb = (const float4*)(Bq + (size_t)i * 16);
            float4 q;
            q = pa[0]; ax0=q.x; ay0=q.y; ax1=q.z; ay1=q.w;
            q = pa[1]; ax2=q.x; ay2=q.y; ax3=q.z; ay3=q.w;
            q = pa[2]; ax4=q.x; ay4=q.y; ax5=q.z; ay5=q.w;
            q = pa[3]; ax6=q.x; ay6=q.y; ax7=q.z; ay7=q.w;
            q = pb[0]; bx0=q.x; by0=q.y; bx1=q.z; by1=q.w;
            q = pb[1]; bx2=q.x; by2=q.y; bx3=q.z; by3=q.w;
            q = pb[2]; bx4=q.x; by4=q.y; bx5=q.z; by5=q.w;
            q = pb[3]; bx6=q.x; by6=q.y; bx7=q.z; by7=q.w;
        }

        // Shoelace areas (input vertex order is CCW; sort_poly = rotation).
        float area_a = 0.5f * ((ax0*ay1-ay0*ax1) + (ax1*ay2-ay1*ax2)
                             + (ax2*ay3-ay2*ax3) + (ax3*ay4-ay3*ax4)
                             + (ax4*ay5-ay4*ax5) + (ax5*ay6-ay5*ax6)
                             + (ax6*ay7-ay6*ax7) + (ax7*ay0-ay7*ax0));
        float area_b = 0.5f * ((bx0*by1-by0*bx1) + (bx1*by2-by1*bx2)
                             + (bx2*by3-by2*bx3) + (bx3*by4-by3*bx4)
                             + (bx4*by5-by4*bx5) + (bx5*by6-by5*bx6)
                             + (bx6*by7-by6*bx7) + (bx7*by0-by7*bx0));

        // ---- Intersection: Green's theorem over clipped edges ----
        float inter2 = 0.f;

        // one half-plane constraint: inside Q iff cross(E_Q, p-V_Q) >= 0
#define HP(QX0,QY0,QX1,QY1) { \
            float ex = (QX1)-(QX0), ey = (QY1)-(QY0); \
            float aa = ex*(Py-(QY0)) - ey*(Px-(QX0)); \
            float bb = ex*Dy - ey*Dx; \
            float tc = __fdividef(-aa, bb); \
            bool bp = bb > 0.f, bn = bb < 0.f; \
            t0 = (bp && tc > t0) ? tc : t0; \
            t1 = (bn && tc < t1) ? tc : t1; \
            empty = empty || (bb == 0.f && aa < 0.f); \
        }

#define HPB HP(bx0,by0,bx1,by1) HP(bx1,by1,bx2,by2) HP(bx2,by2,bx3,by3) \
            HP(bx3,by3,bx4,by4) HP(bx4,by4,bx5,by5) HP(bx5,by5,bx6,by6) \
            HP(bx6,by6,bx7,by7) HP(bx7,by7,bx0,by0)
#define HPA HP(ax0,ay0,ax1,ay1) HP(ax1,ay1,ax2,ay2) HP(ax2,ay2,ax3,ay3) \
            HP(ax3,ay3,ax4,ay4) HP(ax4,ay4,ax5,ay5) HP(ax5,ay5,ax6,ay6) \
            HP(ax6,ay6,ax7,ay7) HP(ax7,ay7,ax0,ay0)

#define EDGE(PX,PY,QX,QY,HPS) { \
            const float Px = (PX), Py = (PY); \
            const float Dx = (QX) - Px, Dy = (QY) - Py; \
            float t0 = 0.f, t1 = 1.f; \
            bool empty = false; \
            HPS \
            t0 = fminf(fmaxf(t0, 0.f), 1.f); \
            t1 = fminf(fmaxf(t1, 0.f), 1.f); \
            bool ok = (t1 > t0) && !empty; \
            float P0x = Px + t0*Dx, P0y = Py + t0*Dy; \
            float P1x = Px + t1*Dx, P1y = Py + t1*Dy; \
            inter2 += ok ? (P0x*P1y - P0y*P1x) : 0.f; \
        }

        EDGE(ax0,ay0,ax1,ay1,HPB) EDGE(ax1,ay1,ax2,ay2,HPB)
        EDGE(ax2,ay2,ax3,ay3,HPB) EDGE(ax3,ay3,ax4,ay4,HPB)
        EDGE(ax4,ay4,ax5,ay5,HPB) EDGE(ax5,ay5,ax6,ay6,HPB)
        EDGE(ax6,ay6,ax7,ay7,HPB) EDGE(ax7,ay7,ax0,ay0,HPB)
        EDGE(bx0,by0,bx1,by1,HPA) EDGE(bx1,by1,bx2,by2,HPA)
        EDGE(bx2,by2,bx3,by3,HPA) EDGE(bx3,by3,bx4,by4,HPA)
        EDGE(bx4,by4,bx5,by5,HPA) EDGE(bx5,by5,bx6,by6,HPA)
        EDGE(bx6,by6,bx7,by7,HPA) EDGE(bx7,by7,bx0,by0,HPA)

        float inter = fmaxf(0.5f * inter2, 0.f);
        float uni = area_a + area_b - inter;
        float iou = __fdividef(inter, uni);

        // ---- Convex hull area of 16 points: scalar Jarvis march ----
        float stx = ax0, sty = ay0;
#define UPD(PX,PY) { \
            bool bsel = ((PY) < sty) || ((PY) == sty && (PX) < stx); \
            stx = bsel ? (PX) : stx; sty = bsel ? (PY) : sty; \
        }
        UPD(ax1,ay1) UPD(ax2,ay2) UPD(ax3,ay3) UPD(ax4,ay4)
        UPD(ax5,ay5) UPD(ax6,ay6) UPD(ax7,ay7)
        UPD(bx0,by0) UPD(bx1,by1) UPD(bx2,by2) UPD(bx3,by3)
        UPD(bx4,by4) UPD(bx5,by5) UPD(bx6,by6) UPD(bx7,by7)

        float cxv = stx, cyv = sty, accH = 0.f;
        bool done = false;
        for (int it = 0; it < 16; ++it) {
            float nx = cxv, ny = cyv, cdx = 0.f, cdy = 0.f;
            bool cv = false;
#define SCAN(PX,PY) { \
                float vx = (PX) - cxv, vy = (PY) - cyv; \
                bool valid = (vx*vx + vy*vy) > 1e-16f; \
                float cr = cdx*vy - cdy*vx; \
                bool take = valid && (!cv || cr < 0.f); \
                nx = take ? (PX) : nx;  ny = take ? (PY) : ny; \
                cdx = take ? vx : cdx;  cdy = take ? vy : cdy; \
                cv = cv || valid; \
            }
            SCAN(ax0,ay0) SCAN(ax1,ay1) SCAN(ax2,ay2) SCAN(ax3,ay3)
            SCAN(ax4,ay4) SCAN(ax5,ay5) SCAN(ax6,ay6) SCAN(ax7,ay7)
            SCAN(bx0,by0) SCAN(bx1,by1) SCAN(bx2,by2) SCAN(bx3,by3)
            SCAN(bx4,by4) SCAN(bx5,by5) SCAN(bx6,by6) SCAN(bx7,by7)
            accH += done ? 0.f : (cxv*ny - cyv*nx);
            done = done || (nx == stx && ny == sty);
            cxv = nx; cyv = ny;
            if (__all(done)) break;
        }
        float ch = 0.5f * accH;

        val = iou - __fdividef(ch - uni, ch);
    }

    // ---- reduction: wave shuffle -> LDS(16B) -> global double atomic ----
    float v = val;
    #pragma unroll
    for (int off = 32; off > 0; off >>= 1) v += __shfl_down(v, off);
    __shared__ float wsum[4];
    int lane = t & 63, wid = t >> 6;
    if (lane == 0) wsum[wid] = v;
    __syncthreads();
    if (t == 0) {
        double bsum = (double)wsum[0] + (double)wsum[1]
                    + (double)wsum[2] + (double)wsum[3];
        atomicAdd(acc, bsum);
        __threadfence();
        unsigned int old = atomicAdd(cnt, 1u);
        if (old == (unsigned int)(nblocks - 1)) {
            double total = atomicAdd(acc, 0.0);   // read after all adds visible
            out[0] = (float)(total / (double)nbatch);
        }
    }
}

extern "C" void kernel_launch(void* const* d_in, const int* in_sizes, int n_in,
                              void* d_out, int out_size, void* d_ws, size_t ws_size,
                              hipStream_t stream) {
    const float* a = (const float*)d_in[0];
    const float* b = (const float*)d_in[1];
    float* out = (float*)d_out;
    int nbatch = in_sizes[0] / 16;
    int nblocks = (nbatch + TPB - 1) / TPB;
    double* acc = (double*)d_ws;                          // [0,8): double sum
    unsigned int* cnt = (unsigned int*)((char*)d_ws + 8); // [8,12): counter
    hipMemsetAsync(d_ws, 0, 16, stream);
    ciou_fused<<<nblocks, TPB, 0, stream>>>(a, b, out, acc, cnt, nbatch, nblocks);
}